// Round 4
// baseline (568.478 us; speedup 1.0000x reference)
//
#include <hip/hip_runtime.h>
#include <hip/hip_bf16.h>

#define NPTS 1048576
#define NCLU 16384
#define NBINS NCLU
#define DF   64
#define H1   128
#define H2   64
#define BP   64                      // points per tile
#define NBLK 768                     // persistent blocks (3 per CU exactly)
#define NTILES (NPTS / BP)           // 16384 tiles, grid-stride
#define K1P  104                     // LDS row stride (u16) for K=96
#define K2P  136                     // LDS row stride (u16) for K=128

typedef __bf16 bf16x8 __attribute__((ext_vector_type(8)));
typedef __bf16 bf16x4 __attribute__((ext_vector_type(4)));
typedef float  f32x4  __attribute__((ext_vector_type(4)));
typedef unsigned short u16x4 __attribute__((ext_vector_type(4)));
typedef unsigned short u16x8 __attribute__((ext_vector_type(8)));

__device__ __forceinline__ unsigned short f2b(float f) {
  unsigned v; __builtin_memcpy(&v, &f, 4);
  v += 0x7fffu + ((v >> 16) & 1u);          // round-to-nearest-even
  return (unsigned short)(v >> 16);
}

// K1: feat fp32 -> bf16 table in ws; also zero the label histogram
__global__ __launch_bounds__(256, 4)
void cvt_feat_zero(const float* __restrict__ f, unsigned short* __restrict__ o,
                   int* __restrict__ hist, int do_hist) {
  int gid = blockIdx.x * 256 + threadIdx.x;
  int i = gid * 4;
  f32x4 v = *(const f32x4*)&f[i];
  u16x4 h;
  #pragma unroll
  for (int j = 0; j < 4; ++j) h[j] = f2b(v[j]);
  *(u16x4*)&o[i] = h;
  if (do_hist && gid < NBINS) hist[gid] = 0;
}

// K2: label histogram (16K bins, L2-resident; 1M device-scope atomics)
__global__ __launch_bounds__(256, 4)
void hist_kernel(const int* __restrict__ labels, int* __restrict__ hist) {
  int i = blockIdx.x * 256 + threadIdx.x;
  atomicAdd(&hist[labels[i]], 1);
}

// K3: exclusive scan of 16384 bins -> cursor (single block, 1024 threads x 16 bins)
__global__ __launch_bounds__(1024)
void scan_kernel(const int* __restrict__ hist, int* __restrict__ cursor) {
  __shared__ int part[1024];
  int t = threadIdx.x;
  int local[16]; int sum = 0;
  #pragma unroll
  for (int j = 0; j < 16; ++j) { local[j] = sum; sum += hist[t * 16 + j]; }
  part[t] = sum;
  __syncthreads();
  for (int ofs = 1; ofs < 1024; ofs <<= 1) {   // Hillis-Steele inclusive scan
    int v = (t >= ofs) ? part[t - ofs] : 0;
    __syncthreads();
    part[t] += v;
    __syncthreads();
  }
  int pre = (t == 0) ? 0 : part[t - 1];
  #pragma unroll
  for (int j = 0; j < 16; ++j) cursor[t * 16 + j] = pre + local[j];
}

// K4: scatter into label-sorted order; pre-compute bf16 deltas (+bias slot).
// centers table (192KB) is L2-hot here since competing traffic is small.
__global__ __launch_bounds__(256, 4)
void scatter_kernel(const int* __restrict__ labels, const float* __restrict__ centers,
                    const float* __restrict__ points, int* __restrict__ cursor,
                    int* __restrict__ perm, int* __restrict__ slab,
                    u16x4* __restrict__ dpts) {
  int i = blockIdx.x * 256 + threadIdx.x;
  int lab = labels[i];
  int pos = atomicAdd(&cursor[lab], 1);
  perm[pos] = i;
  slab[pos] = lab;
  u16x4 d;
  d[0] = f2b(centers[lab * 3 + 0] - points[(long)i * 3 + 0]);
  d[1] = f2b(centers[lab * 3 + 1] - points[(long)i * 3 + 1]);
  d[2] = f2b(centers[lab * 3 + 2] - points[(long)i * 3 + 2]);
  d[3] = 0x3f80;                             // bf16(1.0) -> multiplies the bias row of W1
  dpts[pos] = d;
}

// K5: main fused MLP. mode 2 = label-sorted streams (hot gathers, scattered
// full-line output rows); mode 1 = direct bf16 table; mode 0 = direct fp32.
__global__ __launch_bounds__(256, 3)
void fused_gather_mlp(const float* __restrict__ feat,
                      const int* __restrict__ labels,
                      const float* __restrict__ centers,
                      const float* __restrict__ points,
                      const float* __restrict__ W1,
                      const float* __restrict__ b1,
                      const float* __restrict__ W2,
                      const float* __restrict__ b2,
                      float* __restrict__ out,
                      const unsigned short* __restrict__ featbf,
                      const int* __restrict__ slab,
                      const int* __restrict__ perm,
                      const u16x4* __restrict__ dpts,
                      int mode)
{
  __shared__ __align__(16) unsigned short sW1[H1][K1P];  // W1^T bf16 [n][k], bias row at k=67
  __shared__ __align__(16) unsigned short sH[BP][K2P];   // hidden bf16 (wave-private rows)

  const int t    = threadIdx.x;
  const int w    = t >> 6;
  const int lane = t & 63;
  const int quad = lane >> 4, l16 = lane & 15;
  const int m0   = w * 16;
  const int mrow = m0 + l16;

  // XCD-chunked block swizzle: adjacent swz blocks share the same sorted-label
  // range; chunking keeps them on one XCD's L2. 768 % 8 == 0 -> bijective.
  const int swz = (blockIdx.x & 7) * (NBLK / 8) + (blockIdx.x >> 3);

  // ---------------- one-time staging ----------------
  #pragma unroll
  for (int i = 0; i < 6; ++i) {            // W1 [67][128] (+b1 row 67) -> sW1[n][k]
    int task = t + 256 * i;
    int n = task & 127, kc = task >> 7;
    u16x8 h;
    #pragma unroll
    for (int j = 0; j < 8; ++j) {
      int k = kc * 8 + j;
      float v = (k < 67) ? W1[k * H1 + n] : ((k == 67) ? b1[n] : 0.f);
      h[j] = f2b(v);
    }
    *(u16x8*)&sW1[n][kc * 8] = h;
  }

  bf16x8 w2f[4][4];                        // W2 fragments in registers (loop-invariant)
  #pragma unroll
  for (int nt2 = 0; nt2 < 4; ++nt2)
    #pragma unroll
    for (int ks = 0; ks < 4; ++ks)
      #pragma unroll
      for (int j = 0; j < 8; ++j)
        w2f[nt2][ks][j] = (__bf16)W2[(ks * 32 + quad * 8 + j) * H2 + (nt2 * 16 + l16)];

  f32x4 bias2v[4];
  #pragma unroll
  for (int nt2 = 0; nt2 < 4; ++nt2)
    bias2v[nt2] = *(const f32x4*)&b2[nt2 * 16 + quad * 4];

  __syncthreads();                         // the ONLY barrier

  // ---------------- main loop ----------------
  for (int tile = swz; tile < NTILES; tile += NBLK) {
    const int s = tile * BP + mrow;        // sorted position (mode 2) or point index

    int lab;
    u16x8 a2u = {0, 0, 0, 0, 0, 0, 0, 0};
    long  prow;
    if (mode == 2) {
      lab  = slab[s];
      prow = (long)perm[s];
      if (quad == 0) {
        u16x4 dv = dpts[s];
        a2u[0] = dv[0]; a2u[1] = dv[1]; a2u[2] = dv[2]; a2u[3] = dv[3];
      }
    } else {
      lab  = labels[s];
      prow = (long)s;
      if (quad == 0) {
        a2u[0] = f2b(centers[lab * 3 + 0] - points[(long)s * 3 + 0]);
        a2u[1] = f2b(centers[lab * 3 + 1] - points[(long)s * 3 + 1]);
        a2u[2] = f2b(centers[lab * 3 + 2] - points[(long)s * 3 + 2]);
        a2u[3] = 0x3f80;                   // bias-1 input
      }
    }
    bf16x8 a2; __builtin_memcpy(&a2, &a2u, 16);

    // X fragments: quads split the 128B feature row (no redundancy; L1/L2-hot in mode 2)
    bf16x8 ax0, ax1;
    if (mode >= 1) {
      ax0 = *(const bf16x8*)&featbf[(long)lab * DF + quad * 8];
      ax1 = *(const bf16x8*)&featbf[(long)lab * DF + 32 + quad * 8];
    } else {
      f32x4 v0 = *(const f32x4*)&feat[(long)lab * DF + quad * 8];
      f32x4 v1 = *(const f32x4*)&feat[(long)lab * DF + quad * 8 + 4];
      f32x4 v2 = *(const f32x4*)&feat[(long)lab * DF + 32 + quad * 8];
      f32x4 v3 = *(const f32x4*)&feat[(long)lab * DF + 32 + quad * 8 + 4];
      #pragma unroll
      for (int j = 0; j < 4; ++j) {
        ax0[j] = (__bf16)v0[j]; ax0[j + 4] = (__bf16)v1[j];
        ax1[j] = (__bf16)v2[j]; ax1[j + 4] = (__bf16)v3[j];
      }
    }

    // GEMM1 (swapped): lane ends with h[m=l16][n = nt*16+quad*4+r]
    f32x4 acc1[8];
    #pragma unroll
    for (int i = 0; i < 8; ++i) acc1[i] = (f32x4){0.f, 0.f, 0.f, 0.f};
    #pragma unroll
    for (int nt = 0; nt < 8; ++nt) {
      bf16x8 wa = *(const bf16x8*)&sW1[nt * 16 + l16][quad * 8];
      bf16x8 wb = *(const bf16x8*)&sW1[nt * 16 + l16][32 + quad * 8];
      bf16x8 wc = *(const bf16x8*)&sW1[nt * 16 + l16][64 + quad * 8];
      acc1[nt] = __builtin_amdgcn_mfma_f32_16x16x32_bf16(wa, ax0, acc1[nt], 0, 0, 0);
      acc1[nt] = __builtin_amdgcn_mfma_f32_16x16x32_bf16(wb, ax1, acc1[nt], 0, 0, 0);
      acc1[nt] = __builtin_amdgcn_mfma_f32_16x16x32_bf16(wc, a2,  acc1[nt], 0, 0, 0);
    }
    // epilogue 1: relu -> bf16 -> sH (b64 writes, wave-private)
    #pragma unroll
    for (int nt = 0; nt < 8; ++nt) {
      bf16x4 hv;
      #pragma unroll
      for (int r = 0; r < 4; ++r) {
        float v = acc1[nt][r];
        hv[r] = (__bf16)(v > 0.f ? v : 0.f);
      }
      *(bf16x4*)&sH[m0 + l16][nt * 16 + quad * 4] = hv;
    }

    // GEMM2 (swapped), W2 from registers
    f32x4 acc2[4];
    #pragma unroll
    for (int i = 0; i < 4; ++i) acc2[i] = bias2v[i];
    #pragma unroll
    for (int ks = 0; ks < 4; ++ks) {
      bf16x8 hf = *(const bf16x8*)&sH[m0 + l16][ks * 32 + quad * 8];
      #pragma unroll
      for (int nt2 = 0; nt2 < 4; ++nt2)
        acc2[nt2] = __builtin_amdgcn_mfma_f32_16x16x32_bf16(w2f[nt2][ks], hf, acc2[nt2], 0, 0, 0);
    }
    // epilogue 2: relu -> float4 stores (full 256B row = 2 full L2 lines per point)
    #pragma unroll
    for (int nt2 = 0; nt2 < 4; ++nt2) {
      f32x4 v = acc2[nt2];
      #pragma unroll
      for (int r = 0; r < 4; ++r) v[r] = v[r] > 0.f ? v[r] : 0.f;
      *(f32x4*)&out[prow * H2 + nt2 * 16 + quad * 4] = v;
    }
  }
}

extern "C" void kernel_launch(void* const* d_in, const int* in_sizes, int n_in,
                              void* d_out, int out_size, void* d_ws, size_t ws_size,
                              hipStream_t stream) {
  const float* feat   = (const float*)d_in[0];
  const int*   labels = (const int*)d_in[1];
  const float* cen    = (const float*)d_in[2];
  const float* pts    = (const float*)d_in[3];
  const float* W1     = (const float*)d_in[4];
  const float* b1     = (const float*)d_in[5];
  const float* W2     = (const float*)d_in[6];
  const float* b2     = (const float*)d_in[7];
  float*       outp   = (float*)d_out;

  // workspace layout
  unsigned char* W = (unsigned char*)d_ws;
  const size_t o_featbf = 0;
  const size_t sz_featbf = (size_t)NCLU * DF * 2;              // 2 MB
  const size_t o_hist   = o_featbf + sz_featbf;
  const size_t o_cursor = o_hist + (size_t)NBINS * 4;
  const size_t o_perm   = o_cursor + (size_t)NBINS * 4;
  const size_t o_slab   = o_perm + (size_t)NPTS * 4;
  const size_t o_dpts   = o_slab + (size_t)NPTS * 4;
  const size_t total    = o_dpts + (size_t)NPTS * 8;           // ~18.2 MB

  int mode = (ws_size >= total) ? 2 : (ws_size >= sz_featbf ? 1 : 0);

  unsigned short* featbf = (unsigned short*)(W + o_featbf);
  int*   hist   = (int*)(W + o_hist);
  int*   cursor = (int*)(W + o_cursor);
  int*   perm   = (int*)(W + o_perm);
  int*   slab   = (int*)(W + o_slab);
  u16x4* dpts   = (u16x4*)(W + o_dpts);

  if (mode >= 1)
    cvt_feat_zero<<<dim3(NCLU * DF / (256 * 4)), dim3(256), 0, stream>>>(
        feat, featbf, hist, mode == 2 ? 1 : 0);

  if (mode == 2) {
    hist_kernel<<<dim3(NPTS / 256), dim3(256), 0, stream>>>(labels, hist);
    scan_kernel<<<dim3(1), dim3(1024), 0, stream>>>(hist, cursor);
    scatter_kernel<<<dim3(NPTS / 256), dim3(256), 0, stream>>>(
        labels, cen, pts, cursor, perm, slab, dpts);
  }

  fused_gather_mlp<<<dim3(NBLK), dim3(256), 0, stream>>>(
      feat, labels, cen, pts, W1, b1, W2, b2, outp, featbf, slab, perm, dpts, mode);
}

// Round 5
// 464.474 us; speedup vs baseline: 1.2239x; 1.2239x over previous
//
#include <hip/hip_runtime.h>
#include <hip/hip_bf16.h>

#define NPTS 1048576
#define NCLU 16384
#define DF   64
#define H1   128
#define H2   64
#define BP   64                      // points per tile
#define NBLK 768                     // persistent blocks (3 per CU)
#define NTILES (NPTS / BP)           // 16384 tiles, grid-stride
#define K0P  76                      // LDS row stride (u16) for sX (64 valid cols)
#define K1P  104                     // LDS row stride (u16) for sW1 (K=96)
#define K2P  132                     // LDS row stride (u16) for sH (K=128)

typedef __bf16 bf16x8 __attribute__((ext_vector_type(8)));
typedef __bf16 bf16x4 __attribute__((ext_vector_type(4)));
typedef float  f32x4  __attribute__((ext_vector_type(4)));
typedef unsigned short u16x4 __attribute__((ext_vector_type(4)));
typedef unsigned short u16x8 __attribute__((ext_vector_type(8)));

__device__ __forceinline__ unsigned short f2b(float f) {
  unsigned v; __builtin_memcpy(&v, &f, 4);
  v += 0x7fffu + ((v >> 16) & 1u);          // round-to-nearest-even
  return (unsigned short)(v >> 16);
}

// pre-kernel: feat fp32 [16384][64] -> bf16 u16 same layout in ws
__global__ __launch_bounds__(256, 4)
void cvt_feat(const float* __restrict__ f, unsigned short* __restrict__ o) {
  int i = (blockIdx.x * 256 + threadIdx.x) * 4;
  f32x4 v = *(const f32x4*)&f[i];
  u16x4 h;
  #pragma unroll
  for (int j = 0; j < 4; ++j) h[j] = f2b(v[j]);
  *(u16x4*)&o[i] = h;
}

// Hybrid of the two proven designs:
//  - batched LDS gather (R1, 154us): wave issues 16 labels + 32x16B feature
//    loads back-to-back -> deep memory-level parallelism per wave
//  - swapped-operand GEMMs (R2+): lane ends GEMM1 with h[m=l16][n contiguous]
//    -> b64 sH writes; GEMM2 from register-resident W2 -> coalesced dwordx4 out
//  - b1 folded into W1 (const-1 input at k=67), b2 as accumulator init
//  - LDS 53.2KB -> 3 blocks/CU; 1-tile-ahead label prefetch (plain loads)
__global__ __launch_bounds__(256, 3)
void fused_gather_mlp(const float* __restrict__ feat,
                      const int* __restrict__ labels,
                      const float* __restrict__ centers,
                      const float* __restrict__ points,
                      const float* __restrict__ W1,
                      const float* __restrict__ b1,
                      const float* __restrict__ W2,
                      const float* __restrict__ b2,
                      float* __restrict__ out,
                      const unsigned short* __restrict__ featbf,
                      int use_bf)
{
  __shared__ __align__(16) unsigned short sX[BP][K0P];   // x tile bf16 (wave-private rows)
  __shared__ __align__(16) unsigned short sW1[H1][K1P];  // W1^T bf16 [n][k], bias row at k=67
  __shared__ __align__(16) unsigned short sH[BP][K2P];   // hidden bf16 (wave-private rows)

  const int t    = threadIdx.x;
  const int w    = t >> 6;
  const int lane = t & 63;
  const int quad = lane >> 4, l16 = lane & 15;
  const int m0   = w * 16;                 // this wave's 16-row M tile
  const int mrow = m0 + l16;               // this lane's staging/output row

  // ---------------- one-time staging ----------------
  // W1 [67][128] (+ b1 as row 67) -> sW1[n][k]
  #pragma unroll
  for (int i = 0; i < 6; ++i) {            // 128 n * 12 kc = 1536 tasks
    int task = t + 256 * i;
    int n = task & 127, kc = task >> 7;
    u16x8 h;
    #pragma unroll
    for (int j = 0; j < 8; ++j) {
      int k = kc * 8 + j;
      float v = (k < 67) ? W1[k * H1 + n] : ((k == 67) ? b1[n] : 0.f);
      h[j] = f2b(v);
    }
    *(u16x8*)&sW1[n][kc * 8] = h;
  }

  // W2 -> per-lane register fragments (loop-invariant)
  bf16x8 w2f[4][4];
  #pragma unroll
  for (int nt2 = 0; nt2 < 4; ++nt2)
    #pragma unroll
    for (int ks = 0; ks < 4; ++ks)
      #pragma unroll
      for (int j = 0; j < 8; ++j)
        w2f[nt2][ks][j] = (__bf16)W2[(ks * 32 + quad * 8 + j) * H2 + (nt2 * 16 + l16)];

  // bias2 as accumulator-init: acc2[nt2][r] <-> n2 = nt2*16+quad*4+r
  f32x4 bias2v[4];
  #pragma unroll
  for (int nt2 = 0; nt2 < 4; ++nt2)
    bias2v[nt2] = *(const f32x4*)&b2[nt2 * 16 + quad * 4];

  __syncthreads();                         // the ONLY barrier

  // prologue: this lane's row label for the first tile (quads duplicate -> broadcast)
  int labC = labels[blockIdx.x * BP + mrow];

  // ---------------- main loop: grid-stride tiles, all wave-private ----------------
  for (int tile = blockIdx.x; tile < NTILES; tile += NBLK) {
    const int  p  = tile * BP + mrow;      // this lane's point row
    const int  nt_ = tile + NBLK;
    int labN = 0;
    if (nt_ < NTILES) labN = labels[nt_ * BP + mrow];   // prefetch next tile's label

    // ---- batched gather: lane stages 32B (cols 16q..16q+16) of row mrow ----
    const long fb = (long)labC * DF;
    u16x8 g0, g1;
    if (use_bf) {
      g0 = *(const u16x8*)&featbf[fb + quad * 16];
      g1 = *(const u16x8*)&featbf[fb + quad * 16 + 8];
    } else {
      f32x4 v0 = *(const f32x4*)&feat[fb + quad * 16];
      f32x4 v1 = *(const f32x4*)&feat[fb + quad * 16 + 4];
      f32x4 v2 = *(const f32x4*)&feat[fb + quad * 16 + 8];
      f32x4 v3 = *(const f32x4*)&feat[fb + quad * 16 + 12];
      #pragma unroll
      for (int j = 0; j < 4; ++j) {
        g0[j] = f2b(v0[j]); g0[j + 4] = f2b(v1[j]);
        g1[j] = f2b(v2[j]); g1[j + 4] = f2b(v3[j]);
      }
    }
    // delta fragment (k=64..71) in registers, quad0 only; W1 rows 68..95 are zero
    bf16x8 a2;
    #pragma unroll
    for (int j = 0; j < 8; ++j) a2[j] = (__bf16)0.0f;
    if (quad == 0) {
      a2[0] = (__bf16)(centers[labC * 3 + 0] - points[(long)p * 3 + 0]);
      a2[1] = (__bf16)(centers[labC * 3 + 1] - points[(long)p * 3 + 1]);
      a2[2] = (__bf16)(centers[labC * 3 + 2] - points[(long)p * 3 + 2]);
      a2[3] = (__bf16)1.0f;                // bias-1 input
    }
    // stage to LDS (wave-private; compiler inserts the lgkmcnt before reads)
    *(u16x8*)&sX[mrow][quad * 16]     = g0;
    *(u16x8*)&sX[mrow][quad * 16 + 8] = g1;

    // ---- GEMM1 (swapped): [128n x 96k] . [16m x 96k]^T ----
    bf16x8 ax0 = *(const bf16x8*)&sX[mrow][quad * 8];
    bf16x8 ax1 = *(const bf16x8*)&sX[mrow][32 + quad * 8];
    f32x4 acc1[8];
    #pragma unroll
    for (int i = 0; i < 8; ++i) acc1[i] = (f32x4){0.f, 0.f, 0.f, 0.f};
    #pragma unroll
    for (int nt = 0; nt < 8; ++nt) {
      bf16x8 wa = *(const bf16x8*)&sW1[nt * 16 + l16][quad * 8];
      bf16x8 wb = *(const bf16x8*)&sW1[nt * 16 + l16][32 + quad * 8];
      bf16x8 wc = *(const bf16x8*)&sW1[nt * 16 + l16][64 + quad * 8];
      acc1[nt] = __builtin_amdgcn_mfma_f32_16x16x32_bf16(wa, ax0, acc1[nt], 0, 0, 0);
      acc1[nt] = __builtin_amdgcn_mfma_f32_16x16x32_bf16(wb, ax1, acc1[nt], 0, 0, 0);
      acc1[nt] = __builtin_amdgcn_mfma_f32_16x16x32_bf16(wc, a2,  acc1[nt], 0, 0, 0);
    }
    // epilogue 1: relu -> bf16 -> sH[m=l16][4 contiguous n] (b64 writes)
    #pragma unroll
    for (int nt = 0; nt < 8; ++nt) {
      bf16x4 hv;
      #pragma unroll
      for (int r = 0; r < 4; ++r) {
        float v = acc1[nt][r];
        hv[r] = (__bf16)(v > 0.f ? v : 0.f);
      }
      *(bf16x4*)&sH[mrow][nt * 16 + quad * 4] = hv;
    }

    // ---- GEMM2 (swapped): [64n2 x 128k] . [16m x 128k]^T, W2 from registers ----
    f32x4 acc2[4];
    #pragma unroll
    for (int i = 0; i < 4; ++i) acc2[i] = bias2v[i];
    #pragma unroll
    for (int ks = 0; ks < 4; ++ks) {
      bf16x8 hf = *(const bf16x8*)&sH[mrow][ks * 32 + quad * 8];
      #pragma unroll
      for (int nt2 = 0; nt2 < 4; ++nt2)
        acc2[nt2] = __builtin_amdgcn_mfma_f32_16x16x32_bf16(w2f[nt2][ks], hf, acc2[nt2], 0, 0, 0);
    }
    // epilogue 2: relu -> coalesced float4 stores (lane owns row mrow)
    #pragma unroll
    for (int nt2 = 0; nt2 < 4; ++nt2) {
      f32x4 v = acc2[nt2];
      #pragma unroll
      for (int r = 0; r < 4; ++r) v[r] = v[r] > 0.f ? v[r] : 0.f;
      *(f32x4*)&out[(long)p * H2 + nt2 * 16 + quad * 4] = v;
    }

    labC = labN;                           // rotate prefetched label
  }
}

extern "C" void kernel_launch(void* const* d_in, const int* in_sizes, int n_in,
                              void* d_out, int out_size, void* d_ws, size_t ws_size,
                              hipStream_t stream) {
  const float* feat   = (const float*)d_in[0];
  const int*   labels = (const int*)d_in[1];
  const float* cen    = (const float*)d_in[2];
  const float* pts    = (const float*)d_in[3];
  const float* W1     = (const float*)d_in[4];
  const float* b1     = (const float*)d_in[5];
  const float* W2     = (const float*)d_in[6];
  const float* b2     = (const float*)d_in[7];
  float*       outp   = (float*)d_out;

  const size_t featbf_bytes = (size_t)NCLU * DF * sizeof(unsigned short);  // 2 MB
  int use_bf = (ws_size >= featbf_bytes) ? 1 : 0;
  unsigned short* featbf = (unsigned short*)d_ws;

  if (use_bf)
    cvt_feat<<<dim3(NCLU * DF / (256 * 4)), dim3(256), 0, stream>>>(feat, featbf);

  fused_gather_mlp<<<dim3(NBLK), dim3(256), 0, stream>>>(
      feat, labels, cen, pts, W1, b1, W2, b2, outp, featbf, use_bf);
}

// Round 6
// 385.983 us; speedup vs baseline: 1.4728x; 1.2034x over previous
//
#include <hip/hip_runtime.h>
#include <hip/hip_bf16.h>

#define NPTS 1048576
#define NCLU 16384
#define DF   64
#define H1   128
#define H2   64
#define BP   64        // points per tile
#define NBLK 1024      // persistent blocks (2 per CU)
#define ITERS (NPTS / (BP * NBLK))   // 16 contiguous tiles per block
#define K1P  104       // LDS row stride (u16) for K=96 (67 valid + zero pad)
#define K2P  136       // LDS row stride (u16) for K=128

typedef __bf16 bf16x8 __attribute__((ext_vector_type(8)));
typedef float  f32x4  __attribute__((ext_vector_type(4)));
typedef unsigned short u16x4 __attribute__((ext_vector_type(4)));
typedef unsigned short u16x8 __attribute__((ext_vector_type(8)));

__device__ __forceinline__ unsigned short f2b(float f) {
  unsigned v; __builtin_memcpy(&v, &f, 4);
  v += 0x7fffu + ((v >> 16) & 1u);          // round-to-nearest-even
  return (unsigned short)(v >> 16);
}

// pre-kernel: feat fp32 [16384][64] -> bf16 u16 same layout in ws
__global__ __launch_bounds__(256, 4)
void cvt_feat(const float* __restrict__ f, unsigned short* __restrict__ o) {
  int i = (blockIdx.x * 256 + threadIdx.x) * 4;
  f32x4 v = *(const f32x4*)&f[i];
  u16x4 h;
  #pragma unroll
  for (int j = 0; j < 4; ++j) h[j] = f2b(v[j]);
  *(u16x4*)&o[i] = h;
}

// Exact R1 (154us-proven) structure. ONE change: GEMM2 operands swapped
// (acc2 = mfma(W2frag, Hfrag)) so each lane ends with 4 contiguous output
// floats -> 4 coalesced dwordx4 stores instead of 16 scalar stores.
// bias2 folded into the accumulator init.
__global__ __launch_bounds__(256, 2)
void fused_gather_mlp(const float* __restrict__ feat,
                      const int* __restrict__ labels,
                      const float* __restrict__ centers,
                      const float* __restrict__ points,
                      const float* __restrict__ W1,
                      const float* __restrict__ b1,
                      const float* __restrict__ W2,
                      const float* __restrict__ b2,
                      float* __restrict__ out,
                      const unsigned short* __restrict__ featbf,
                      int use_bf)
{
  __shared__ __align__(16) unsigned short sX[BP][K1P];   // x tile bf16 (wave-private rows)
  __shared__ __align__(16) unsigned short sW1[H1][K1P];  // W1^T bf16 [n][k]
  __shared__ __align__(16) unsigned short sH[BP][K2P];   // hidden bf16 (wave-private rows)
  __shared__ __align__(16) unsigned short sW2[H2][K2P];  // W2^T bf16 [n][k]
  __shared__ __align__(16) float sB1[H1];

  const int t    = threadIdx.x;
  const int w    = t >> 6;
  const int lane = t & 63;
  const int quad = lane >> 4, l16 = lane & 15;
  const int m0   = w * 16;                 // this wave's 16-row M tile

  // ---------------- one-time staging (conflict-free, chunk-granular) ----------------
  if (t < 32) *(f32x4*)&sB1[t * 4] = *(const f32x4*)&b1[t * 4];

  // W1 [67][128] -> sW1[n][k]
  #pragma unroll
  for (int i = 0; i < 6; ++i) {            // 128 n * 12 kc = 1536 tasks
    int task = t + 256 * i;
    int n = task & 127, kc = task >> 7;
    u16x8 h;
    #pragma unroll
    for (int j = 0; j < 8; ++j) {
      int k = kc * 8 + j;
      float v = (k < 67) ? W1[k * H1 + n] : 0.f;
      h[j] = f2b(v);
    }
    *(u16x8*)&sW1[n][kc * 8] = h;
  }
  // W2 [128][64] -> sW2[n][k]
  #pragma unroll
  for (int i = 0; i < 4; ++i) {            // 64 n * 16 kc = 1024 tasks
    int task = t + 256 * i;
    int n = task & 63, kc = task >> 6;
    u16x8 h;
    #pragma unroll
    for (int j = 0; j < 8; ++j) h[j] = f2b(W2[(kc * 8 + j) * H2 + n]);
    *(u16x8*)&sW2[n][kc * 8] = h;
  }
  // zero this wave's sX pad chunks 9..11 (k=72..95) once; chunk 8 rewritten every iter
  if (lane < 48) {
    int r = lane & 15, c = 9 + (lane >> 4);
    u16x8 z = {0, 0, 0, 0, 0, 0, 0, 0};
    *(u16x8*)&sX[m0 + r][c * 8] = z;
  }

  // bias2 as accumulator-init: acc2[nt2][r] <-> n2 = nt2*16+quad*4+r (tiny global reads)
  f32x4 bias2v[4];
  #pragma unroll
  for (int nt2 = 0; nt2 < 4; ++nt2)
    bias2v[nt2] = *(const f32x4*)&b2[nt2 * 16 + quad * 4];

  __syncthreads();                         // the ONLY barrier

  // hoist per-lane bias1 (loop-invariant; epi1 column n = nt*16+l16)
  float bias1[8];
  #pragma unroll
  for (int nt = 0; nt < 8; ++nt) bias1[nt] = sB1[nt * 16 + l16];

  // ---------------- main loop: 16 contiguous tiles, no barriers (all wave-private) ----------------
  for (int it = 0; it < ITERS; ++it) {
    const int p0 = (blockIdx.x * ITERS + it) * BP;

    // gather: this wave fills sX rows m0..m0+15, chunks 0..7 (k=0..63)
    #pragma unroll
    for (int i = 0; i < 2; ++i) {          // 16 rows * 8 chunks = 128 tasks / 64 lanes
      int task = lane + 64 * i;
      int row = task >> 3, kc = task & 7;
      int lab = labels[p0 + m0 + row];
      if (use_bf) {
        *(u16x8*)&sX[m0 + row][kc * 8] = *(const u16x8*)&featbf[lab * DF + kc * 8];
      } else {
        f32x4 v0 = *(const f32x4*)&feat[lab * DF + kc * 8];
        f32x4 v1 = *(const f32x4*)&feat[lab * DF + kc * 8 + 4];
        u16x8 h;
        #pragma unroll
        for (int j = 0; j < 4; ++j) { h[j] = f2b(v0[j]); h[j + 4] = f2b(v1[j]); }
        *(u16x8*)&sX[m0 + row][kc * 8] = h;
      }
    }
    // chunk 8: coord diffs + zeros (k=64..71)
    if (lane < 16) {
      int row = lane, p = p0 + m0 + row;
      int lab = labels[p];
      u16x8 h = {0, 0, 0, 0, 0, 0, 0, 0};
      #pragma unroll
      for (int j = 0; j < 3; ++j) h[j] = f2b(centers[lab * 3 + j] - points[p * 3 + j]);
      *(u16x8*)&sX[m0 + row][DF] = h;
    }

    // GEMM1: [16,96] x [96,128] (unswapped, as in R1)
    f32x4 acc[8];
    #pragma unroll
    for (int i = 0; i < 8; ++i) acc[i] = (f32x4){0.f, 0.f, 0.f, 0.f};
    #pragma unroll
    for (int ks = 0; ks < 3; ++ks) {
      int k0 = ks * 32 + quad * 8;
      bf16x8 a = *(const bf16x8*)&sX[m0 + l16][k0];
      #pragma unroll
      for (int nt = 0; nt < 8; ++nt) {
        bf16x8 b = *(const bf16x8*)&sW1[nt * 16 + l16][k0];
        acc[nt] = __builtin_amdgcn_mfma_f32_16x16x32_bf16(a, b, acc[nt], 0, 0, 0);
      }
    }
    // epilogue 1: bias + relu -> bf16 -> sH (wave-private; C[m=quad*4+r][n=nt*16+l16])
    #pragma unroll
    for (int nt = 0; nt < 8; ++nt) {
      int n = nt * 16 + l16;
      #pragma unroll
      for (int r = 0; r < 4; ++r) {
        float v = acc[nt][r] + bias1[nt];
        v = v > 0.f ? v : 0.f;
        sH[m0 + quad * 4 + r][n] = f2b(v);
      }
    }

    // GEMM2 (SWAPPED): acc2[nt2] = mfma(W2frag, Hfrag) -> lane holds
    // out[m=l16][n2 = nt2*16 + quad*4 + r], 4 contiguous floats per acc block
    f32x4 acc2[4];
    #pragma unroll
    for (int i = 0; i < 4; ++i) acc2[i] = bias2v[i];
    #pragma unroll
    for (int ks = 0; ks < 4; ++ks) {
      int k0 = ks * 32 + quad * 8;
      bf16x8 hf = *(const bf16x8*)&sH[m0 + l16][k0];
      #pragma unroll
      for (int nt2 = 0; nt2 < 4; ++nt2) {
        bf16x8 wf = *(const bf16x8*)&sW2[nt2 * 16 + l16][k0];
        acc2[nt2] = __builtin_amdgcn_mfma_f32_16x16x32_bf16(wf, hf, acc2[nt2], 0, 0, 0);
      }
    }
    // epilogue 2: relu -> 4x coalesced dwordx4 stores (lane owns row m0+l16)
    const long prow = (long)(p0 + m0 + l16) * H2;
    #pragma unroll
    for (int nt2 = 0; nt2 < 4; ++nt2) {
      f32x4 v = acc2[nt2];
      #pragma unroll
      for (int r = 0; r < 4; ++r) v[r] = v[r] > 0.f ? v[r] : 0.f;
      *(f32x4*)&out[prow + nt2 * 16 + quad * 4] = v;
    }
  }
}

extern "C" void kernel_launch(void* const* d_in, const int* in_sizes, int n_in,
                              void* d_out, int out_size, void* d_ws, size_t ws_size,
                              hipStream_t stream) {
  const float* feat   = (const float*)d_in[0];
  const int*   labels = (const int*)d_in[1];
  const float* cen    = (const float*)d_in[2];
  const float* pts    = (const float*)d_in[3];
  const float* W1     = (const float*)d_in[4];
  const float* b1     = (const float*)d_in[5];
  const float* W2     = (const float*)d_in[6];
  const float* b2     = (const float*)d_in[7];
  float*       outp   = (float*)d_out;

  const size_t featbf_bytes = (size_t)NCLU * DF * sizeof(unsigned short);  // 2 MB
  int use_bf = (ws_size >= featbf_bytes) ? 1 : 0;
  unsigned short* featbf = (unsigned short*)d_ws;

  if (use_bf)
    cvt_feat<<<dim3(NCLU * DF / (256 * 4)), dim3(256), 0, stream>>>(feat, featbf);

  fused_gather_mlp<<<dim3(NBLK), dim3(256), 0, stream>>>(
      feat, labels, cen, pts, W1, b1, W2, b2, outp, featbf, use_bf);
}